// Round 1
// baseline (1934.667 us; speedup 1.0000x reference)
//
#include <hip/hip_runtime.h>
#include <cstdint>
#include <cstddef>

#define DEPTH 6
#define NB    16
#define NSEQ  512
#define EMB   1024
#define NHEAD 16
#define HDIM  64
#define FFD   2048
#define NTOK  (NB * NSEQ)   // 8192

typedef unsigned short u16;
using bf16x8 = __attribute__((ext_vector_type(8))) __bf16;
using f32x4  = __attribute__((ext_vector_type(4))) float;
using u16x4  = __attribute__((ext_vector_type(4))) u16;

typedef __attribute__((address_space(1))) uint32_t* as1_u32p;
typedef __attribute__((address_space(3))) uint32_t* as3_u32p;

__device__ __forceinline__ u16 f2bf(float f) {
  union { float f; uint32_t u; } v; v.f = f;
  uint32_t u = v.u;
  return (u16)((u + 0x7FFFu + ((u >> 16) & 1u)) >> 16);
}

__device__ __forceinline__ void gload_lds16(const u16* g, u16* l) {
  void* gp = const_cast<u16*>(g);
  __builtin_amdgcn_global_load_lds((as1_u32p)gp, (as3_u32p)l, 16, 0, 0);
}

// Stage a 16KB tile (rows of ROWBYTES bytes) global->LDS, linear LDS dest,
// XOR-swizzled global source so that reads with byte^((row&7)<<4) are
// bank-conflict-free (guide rule #21: swizzle source+read, dest linear).
template<int ROWBYTES>
__device__ __forceinline__ void stage16k(const u16* g0, int ldk, u16* lds) {
  int t = threadIdx.x;
#pragma unroll
  for (int i = 0; i < 4; ++i) {
    int off = (i * 256 + t) * 16;          // LDS byte offset
    int row = off / ROWBYTES;
    int pc  = (off % ROWBYTES) >> 4;
    int lc  = pc ^ (row & 7);
    gload_lds16(g0 + (size_t)row * ldk + lc * 8, lds + (off >> 1));
  }
}

// ---------------- weight prep: fp32 [K][N] -> bf16 [N][K] (B^T layout) ----
__global__ __launch_bounds__(256)
void wprep_k(const float* __restrict__ W, u16* __restrict__ Wt,
             int K, int N, size_t inL, size_t outL, size_t outOff)
{
  int ntiles = N >> 6, ktiles = K >> 6;
  int bid = blockIdx.x;
  int l = bid / (ktiles * ntiles);
  int r = bid % (ktiles * ntiles);
  int kt = r / ntiles, nt = r % ntiles;
  const float* in = W + (size_t)l * inL + (size_t)(kt * 64) * N + nt * 64;
  u16* out = Wt + (size_t)l * outL + outOff + (size_t)(nt * 64) * K + kt * 64;
  __shared__ float tile[64][65];
  int t = threadIdx.x;
  int tr = t >> 4, tc = (t & 15) * 4;
#pragma unroll
  for (int i = 0; i < 4; ++i) {
    f32x4 v = *(const f32x4*)(in + (size_t)(tr + i * 16) * N + tc);
    tile[tr + i * 16][tc + 0] = v[0];
    tile[tr + i * 16][tc + 1] = v[1];
    tile[tr + i * 16][tc + 2] = v[2];
    tile[tr + i * 16][tc + 3] = v[3];
  }
  __syncthreads();
#pragma unroll
  for (int i = 0; i < 4; ++i) {
    int nr = tr + i * 16;
    u16x4 o;
    o[0] = f2bf(tile[tc + 0][nr]);
    o[1] = f2bf(tile[tc + 1][nr]);
    o[2] = f2bf(tile[tc + 2][nr]);
    o[3] = f2bf(tile[tc + 3][nr]);
    *(u16x4*)(out + (size_t)nr * K + tc) = o;
  }
}

// ---------------- embed: concat cls + pos add ------------------------------
__global__ __launch_bounds__(256)
void embed_k(const float* __restrict__ x, const float* __restrict__ cls,
             const float* __restrict__ pos, float* __restrict__ H)
{
  int row = blockIdx.x, t = threadIdx.x;
  int b_ = row >> 9, n = row & 511;
  int c = t * 4;
  f32x4 p = *(const f32x4*)(pos + (size_t)n * EMB + c);
  f32x4 s;
  if (n == 0) s = *(const f32x4*)(cls + c);
  else        s = *(const f32x4*)(x + ((size_t)b_ * 511 + (n - 1)) * EMB + c);
  f32x4 o = s + p;
  *(f32x4*)(H + (size_t)row * EMB + c) = o;
}

// ---------------- layernorm: fp32 h -> bf16 xn ----------------------------
__global__ __launch_bounds__(256)
void ln_k(const float* __restrict__ H, const float* __restrict__ g,
          const float* __restrict__ b, u16* __restrict__ out)
{
  int row = blockIdx.x, t = threadIdx.x;
  const float* hp = H + (size_t)row * EMB;
  f32x4 v = *(const f32x4*)(hp + t * 4);
  float s  = v[0] + v[1] + v[2] + v[3];
  float ss = v[0]*v[0] + v[1]*v[1] + v[2]*v[2] + v[3]*v[3];
#pragma unroll
  for (int m = 1; m <= 32; m <<= 1) { s += __shfl_xor(s, m); ss += __shfl_xor(ss, m); }
  __shared__ float red[8];
  if ((t & 63) == 0) { red[(t >> 6) * 2] = s; red[(t >> 6) * 2 + 1] = ss; }
  __syncthreads();
  float S  = red[0] + red[2] + red[4] + red[6];
  float SS = red[1] + red[3] + red[5] + red[7];
  float mean = S * (1.0f / EMB);
  float var  = SS * (1.0f / EMB) - mean * mean;
  float rs = rsqrtf(var + 1e-5f);
  f32x4 gg = *(const f32x4*)(g + t * 4);
  f32x4 bb = *(const f32x4*)(b + t * 4);
  u16x4 o;
#pragma unroll
  for (int i = 0; i < 4; ++i) o[i] = f2bf((v[i] - mean) * rs * gg[i] + bb[i]);
  *(u16x4*)(out + (size_t)row * EMB + t * 4) = o;
}

// ---------------- GEMM: C[8192][N] = A[8192][K] * Bt[N][K]^T --------------
// EPI: 0=QKV scatter(q,k,vT bf16)  1=+resid->H(f32)  2=+bias,gelu->outB(bf16)
//      3=+bias+resid->H(f32)
template<int EPI>
__global__ __launch_bounds__(256, 2)
void gemm_k(const u16* __restrict__ A, const u16* __restrict__ Bt,
            int N, int K,
            const float* __restrict__ bias, float* __restrict__ H,
            u16* __restrict__ outB,
            u16* __restrict__ qo, u16* __restrict__ ko, u16* __restrict__ vto)
{
  __shared__ u16 sm[2][2][128 * 64];   // 64 KB, double buffered A/B tiles
  int bid = blockIdx.x;
  int bm = bid & 63, bn = bid >> 6;
  int t = threadIdx.x, lane = t & 63, w = t >> 6;
  int wm = w >> 1, wn = w & 1;
  const u16* Ab = A  + (size_t)(bm * 128) * K;
  const u16* Bb = Bt + (size_t)(bn * 128) * K;
  int nkt = K >> 6;

  stage16k<128>(Ab, K, &sm[0][0][0]);
  stage16k<128>(Bb, K, &sm[0][1][0]);
  __syncthreads();

  const f32x4 vzero = {0.f, 0.f, 0.f, 0.f};
  f32x4 acc[4][4];
#pragma unroll
  for (int i = 0; i < 4; ++i)
#pragma unroll
    for (int j = 0; j < 4; ++j) acc[i][j] = vzero;

  int r0 = lane & 15;
  int kk0 = (lane >> 4) * 8;

  for (int kt = 0; kt < nkt; ++kt) {
    int cur = kt & 1;
    if (kt + 1 < nkt) {
      stage16k<128>(Ab + (kt + 1) * 64, K, &sm[cur ^ 1][0][0]);
      stage16k<128>(Bb + (kt + 1) * 64, K, &sm[cur ^ 1][1][0]);
    }
    const char* smA = (const char*)&sm[cur][0][0];
    const char* smB = (const char*)&sm[cur][1][0];
#pragma unroll
    for (int ks = 0; ks < 2; ++ks) {
      int kk = ks * 32 + kk0;
      bf16x8 a[4], b[4];
#pragma unroll
      for (int mf = 0; mf < 4; ++mf) {
        int row = wm * 64 + mf * 16 + r0;
        a[mf] = *(const bf16x8*)(smA + row * 128 + ((kk * 2) ^ ((row & 7) << 4)));
      }
#pragma unroll
      for (int nf = 0; nf < 4; ++nf) {
        int row = wn * 64 + nf * 16 + r0;
        b[nf] = *(const bf16x8*)(smB + row * 128 + ((kk * 2) ^ ((row & 7) << 4)));
      }
#pragma unroll
      for (int mf = 0; mf < 4; ++mf)
#pragma unroll
        for (int nf = 0; nf < 4; ++nf)
          acc[mf][nf] = __builtin_amdgcn_mfma_f32_16x16x32_bf16(a[mf], b[nf], acc[mf][nf], 0, 0, 0);
    }
    __syncthreads();
  }

  int m0 = bm * 128 + wm * 64;
  int n0 = bn * 128 + wn * 64;
#pragma unroll
  for (int mf = 0; mf < 4; ++mf) {
#pragma unroll
    for (int nf = 0; nf < 4; ++nf) {
#pragma unroll
      for (int j = 0; j < 4; ++j) {
        int row = m0 + mf * 16 + (lane >> 4) * 4 + j;
        int col = n0 + nf * 16 + (lane & 15);
        float v = acc[mf][nf][j];
        if (EPI == 0) {
          int which = col >> 10, c = col & 1023;
          int hh = c >> 6, d = c & 63;
          int b_ = row >> 9, n_ = row & 511;
          size_t bh = (size_t)(b_ * NHEAD + hh);
          if (which == 0)      qo[(bh * NSEQ + n_) * HDIM + d]  = f2bf(v);
          else if (which == 1) ko[(bh * NSEQ + n_) * HDIM + d]  = f2bf(v);
          else                 vto[(bh * HDIM + d) * NSEQ + n_] = f2bf(v);
        } else if (EPI == 1) {
          size_t idx = (size_t)row * EMB + col;
          H[idx] = v + H[idx];
        } else if (EPI == 2) {
          float xg = v + bias[col];
          float ge = 0.5f * xg * (1.0f + erff(xg * 0.70710678118654752f));
          outB[(size_t)row * FFD + col] = f2bf(ge);
        } else {
          size_t idx = (size_t)row * EMB + col;
          H[idx] = v + bias[col] + H[idx];
        }
      }
    }
  }
}

// ---------------- fused attention -----------------------------------------
// grid: (B*H)*8 blocks; block = 4 waves, each wave owns 16 q-rows.
// Q,K: [bh][512][64] bf16; Vt: [bh][64][512] bf16; AO: [b*512+n][1024] bf16
__global__ __launch_bounds__(256, 1)
void attn_k(const u16* __restrict__ Q, const u16* __restrict__ Kk,
            const u16* __restrict__ Vt, u16* __restrict__ AO)
{
  __shared__ u16 kv[2][8192];   // 32 KB staging (K chunks, then V chunks)
  __shared__ u16 Pl[4][8192];   // 64 KB: per-wave P[16][512] bf16, swizzled
  int bid = blockIdx.x;
  int bh = bid >> 3, qt = bid & 7;
  int t = threadIdx.x, lane = t & 63, w = t >> 6;
  const u16* Kb = Kk + (size_t)bh * (NSEQ * HDIM);
  const u16* Vb = Vt + (size_t)bh * (HDIM * NSEQ);
  int r0 = lane & 15, kk0 = (lane >> 4) * 8;

  int qrow = qt * 64 + w * 16 + r0;
  const u16* Qp = Q + ((size_t)bh * NSEQ + qrow) * HDIM;
  bf16x8 qf0 = *(const bf16x8*)(Qp + kk0);
  bf16x8 qf1 = *(const bf16x8*)(Qp + 32 + kk0);

  const f32x4 vzero = {0.f, 0.f, 0.f, 0.f};
  f32x4 accS[32];
#pragma unroll
  for (int f = 0; f < 32; ++f) accS[f] = vzero;

  // ---- S = Q K^T over 4 chunks of 128 keys ----
  stage16k<128>(Kb, HDIM, &kv[0][0]);
  __syncthreads();
#pragma unroll
  for (int kt = 0; kt < 4; ++kt) {
    if (kt < 3) stage16k<128>(Kb + (size_t)(kt + 1) * 128 * HDIM, HDIM, &kv[(kt + 1) & 1][0]);
    const char* smK = (const char*)&kv[kt & 1][0];
#pragma unroll
    for (int nfl = 0; nfl < 8; ++nfl) {
      int krow = nfl * 16 + r0;
      int swz = (krow & 7) << 4;
      bf16x8 b0 = *(const bf16x8*)(smK + krow * 128 + (((kk0)      * 2) ^ swz));
      bf16x8 b1 = *(const bf16x8*)(smK + krow * 128 + (((32 + kk0) * 2) ^ swz));
      accS[kt * 8 + nfl] = __builtin_amdgcn_mfma_f32_16x16x32_bf16(qf0, b0, accS[kt * 8 + nfl], 0, 0, 0);
      accS[kt * 8 + nfl] = __builtin_amdgcn_mfma_f32_16x16x32_bf16(qf1, b1, accS[kt * 8 + nfl], 0, 0, 0);
    }
    __syncthreads();
  }

  // prefetch V chunk 0 under the softmax
  stage16k<256>(Vb, NSEQ, &kv[0][0]);

  // ---- softmax over 512 keys (rows live in 16-lane groups) ----
  float mx[4], den[4], rden[4];
#pragma unroll
  for (int j = 0; j < 4; ++j) {
    float m = -1e30f;
#pragma unroll
    for (int f = 0; f < 32; ++f) m = fmaxf(m, accS[f][j]);
    m = fmaxf(m, __shfl_xor(m, 1));
    m = fmaxf(m, __shfl_xor(m, 2));
    m = fmaxf(m, __shfl_xor(m, 4));
    m = fmaxf(m, __shfl_xor(m, 8));
    mx[j] = m;
    den[j] = 0.f;
  }
#pragma unroll
  for (int f = 0; f < 32; ++f)
#pragma unroll
    for (int j = 0; j < 4; ++j) {
      float p = __expf((accS[f][j] - mx[j]) * 0.03125f);  // /sqrt(E)=32
      accS[f][j] = p;
      den[j] += p;
    }
#pragma unroll
  for (int j = 0; j < 4; ++j) {
    float d = den[j];
    d += __shfl_xor(d, 1); d += __shfl_xor(d, 2);
    d += __shfl_xor(d, 4); d += __shfl_xor(d, 8);
    rden[j] = 1.0f / d;
  }

  // ---- write unnormalized P (bf16) to per-wave LDS, swizzled rows -------
  char* Pw = (char*)&Pl[w][0];
#pragma unroll
  for (int f = 0; f < 32; ++f)
#pragma unroll
    for (int j = 0; j < 4; ++j) {
      int ql = (lane >> 4) * 4 + j;
      int key = f * 16 + r0;
      *(u16*)(Pw + ql * 1024 + ((key * 2) ^ ((ql & 7) << 4))) = f2bf(accS[f][j]);
    }
  __syncthreads();   // V chunk0 staged + P visible

  // ---- O = P V over 4 chunks of 128 keys ----
  f32x4 accO[4];
#pragma unroll
  for (int nf = 0; nf < 4; ++nf) accO[nf] = vzero;
  const char* Pr = (const char*)&Pl[w][0];
  int pswz = (r0 & 7) << 4;
#pragma unroll
  for (int kt = 0; kt < 4; ++kt) {
    if (kt < 3) stage16k<256>(Vb + (kt + 1) * 128, NSEQ, &kv[(kt + 1) & 1][0]);
    const char* smV = (const char*)&kv[kt & 1][0];
#pragma unroll
    for (int ks = 0; ks < 4; ++ks) {
      int keyl = kt * 128 + ks * 32 + kk0;
      bf16x8 pa = *(const bf16x8*)(Pr + r0 * 1024 + ((keyl * 2) ^ pswz));
#pragma unroll
      for (int nf = 0; nf < 4; ++nf) {
        int d = nf * 16 + r0;
        int kkv = ks * 32 + kk0;
        bf16x8 vb = *(const bf16x8*)(smV + d * 256 + ((kkv * 2) ^ ((d & 7) << 4)));
        accO[nf] = __builtin_amdgcn_mfma_f32_16x16x32_bf16(pa, vb, accO[nf], 0, 0, 0);
      }
    }
    __syncthreads();
  }

  // ---- epilogue: normalize, scatter back to [b][n][h*64+d] --------------
  int b_ = bh >> 4, hh = bh & 15;
#pragma unroll
  for (int nf = 0; nf < 4; ++nf)
#pragma unroll
    for (int j = 0; j < 4; ++j) {
      int ql = (lane >> 4) * 4 + j;
      int tok = qt * 64 + w * 16 + ql;
      int col = hh * 64 + nf * 16 + r0;
      AO[((size_t)(b_ * NSEQ + tok)) * EMB + col] = f2bf(accO[nf][j] * rden[j]);
    }
}

// ---------------- launch ---------------------------------------------------
extern "C" void kernel_launch(void* const* d_in, const int* in_sizes, int n_in,
                              void* d_out, int out_size, void* d_ws, size_t ws_size,
                              hipStream_t stream)
{
  const float* x    = (const float*)d_in[0];
  const float* cls  = (const float*)d_in[1];
  const float* pos  = (const float*)d_in[2];
  const float* Wq   = (const float*)d_in[3];
  const float* Wk   = (const float*)d_in[4];
  const float* Wv   = (const float*)d_in[5];
  const float* Wp   = (const float*)d_in[6];
  const float* ln1g = (const float*)d_in[7];
  const float* ln1b = (const float*)d_in[8];
  const float* ln2g = (const float*)d_in[9];
  const float* ln2b = (const float*)d_in[10];
  const float* W1   = (const float*)d_in[11];
  const float* b1   = (const float*)d_in[12];
  const float* W2   = (const float*)d_in[13];
  const float* b2   = (const float*)d_in[14];
  float* H = (float*)d_out;          // residual stream lives in d_out (fp32)

  char* ws = (char*)d_ws;            // 160 MiB used
  u16* wqkv = (u16*)(ws + 0);                // [6][3072][1024] bf16 (B^T)
  u16* wp   = (u16*)(ws + 37748736);         // [6][1024][1024]
  u16* w1t  = (u16*)(ws + 50331648);         // [6][2048][1024]
  u16* w2t  = (u16*)(ws + 75497472);         // [6][1024][2048]
  u16* xn   = (u16*)(ws + 100663296);        // [8192][1024] (also attn out)
  u16* qb   = (u16*)(ws + 117440512);        // [256][512][64]
  u16* kb   = (u16*)(ws + 134217728);        // [256][512][64]
  u16* vtb  = (u16*)(ws + 150994944);        // [256][64][512]
  u16* ffb  = qb;                            // [8192][2048] aliases q+k

  wprep_k<<<1536, 256, 0, stream>>>(Wq, wqkv, 1024, 1024, 1048576, 3145728, 0);
  wprep_k<<<1536, 256, 0, stream>>>(Wk, wqkv, 1024, 1024, 1048576, 3145728, 1048576);
  wprep_k<<<1536, 256, 0, stream>>>(Wv, wqkv, 1024, 1024, 1048576, 3145728, 2097152);
  wprep_k<<<1536, 256, 0, stream>>>(Wp, wp,   1024, 1024, 1048576, 1048576, 0);
  wprep_k<<<3072, 256, 0, stream>>>(W1, w1t,  1024, 2048, 2097152, 2097152, 0);
  wprep_k<<<3072, 256, 0, stream>>>(W2, w2t,  2048, 1024, 2097152, 2097152, 0);

  embed_k<<<NTOK, 256, 0, stream>>>(x, cls, pos, H);

  for (int l = 0; l < DEPTH; ++l) {
    ln_k<<<NTOK, 256, 0, stream>>>(H, ln1g + l * EMB, ln1b + l * EMB, xn);
    gemm_k<0><<<64 * 24, 256, 0, stream>>>(xn, wqkv + (size_t)l * 3145728, 3072, 1024,
                                           nullptr, nullptr, nullptr, qb, kb, vtb);
    attn_k<<<2048, 256, 0, stream>>>(qb, kb, vtb, xn);
    gemm_k<1><<<64 * 8, 256, 0, stream>>>(xn, wp + (size_t)l * 1048576, 1024, 1024,
                                          nullptr, H, nullptr, nullptr, nullptr, nullptr);
    ln_k<<<NTOK, 256, 0, stream>>>(H, ln2g + l * EMB, ln2b + l * EMB, xn);
    gemm_k<2><<<64 * 16, 256, 0, stream>>>(xn, w1t + (size_t)l * 2097152, 2048, 1024,
                                           b1 + l * FFD, nullptr, ffb, nullptr, nullptr, nullptr);
    gemm_k<3><<<64 * 8, 256, 0, stream>>>(ffb, w2t + (size_t)l * 2097152, 1024, 2048,
                                          b2 + l * EMB, H, nullptr, nullptr, nullptr, nullptr);
  }
}

// Round 2
// 1554.742 us; speedup vs baseline: 1.2444x; 1.2444x over previous
//
#include <hip/hip_runtime.h>
#include <cstdint>
#include <cstddef>

#define DEPTH 6
#define NB    16
#define NSEQ  512
#define EMB   1024
#define NHEAD 16
#define HDIM  64
#define FFD   2048
#define NTOK  (NB * NSEQ)   // 8192

typedef unsigned short u16;
using bf16x8 = __attribute__((ext_vector_type(8))) __bf16;
using f32x4  = __attribute__((ext_vector_type(4))) float;
using u16x4  = __attribute__((ext_vector_type(4))) u16;

typedef __attribute__((address_space(1))) uint32_t* as1_u32p;
typedef __attribute__((address_space(3))) uint32_t* as3_u32p;
typedef __attribute__((address_space(3))) u16*      as3_u16p;

__device__ __forceinline__ u16 f2bf(float f) {
  union { float f; uint32_t u; } v; v.f = f;
  uint32_t u = v.u;
  return (u16)((u + 0x7FFFu + ((u >> 16) & 1u)) >> 16);
}

__device__ __forceinline__ void gload_lds16(const u16* g, u16* l) {
  void* gp = const_cast<u16*>(g);
  __builtin_amdgcn_global_load_lds((as1_u32p)gp, (as3_u32p)l, 16, 0, 0);
}

// Stage a 16KB tile (rows of ROWBYTES bytes) global->LDS, linear LDS dest,
// XOR-swizzled global source so that reads with byte^((row&7)<<4) are
// bank-conflict-free (rule #21: swizzle source+read, dest linear).
template<int ROWBYTES>
__device__ __forceinline__ void stage16k(const u16* g0, int ldk, u16* lds) {
  int t = threadIdx.x;
#pragma unroll
  for (int i = 0; i < 4; ++i) {
    int off = (i * 256 + t) * 16;          // LDS byte offset
    int row = off / ROWBYTES;
    int pc  = (off % ROWBYTES) >> 4;
    int lc  = pc ^ (row & 7);
    gload_lds16(g0 + (size_t)row * ldk + lc * 8, lds + (off >> 1));
  }
}

// ---------------- weight prep: fp32 [K][N] -> bf16 [N][K] (B^T layout) ----
__global__ __launch_bounds__(256)
void wprep_k(const float* __restrict__ W, u16* __restrict__ Wt,
             int K, int N, size_t inL, size_t outL, size_t outOff)
{
  int ntiles = N >> 6, ktiles = K >> 6;
  int bid = blockIdx.x;
  int l = bid / (ktiles * ntiles);
  int r = bid % (ktiles * ntiles);
  int kt = r / ntiles, nt = r % ntiles;
  const float* in = W + (size_t)l * inL + (size_t)(kt * 64) * N + nt * 64;
  u16* out = Wt + (size_t)l * outL + outOff + (size_t)(nt * 64) * K + kt * 64;
  __shared__ float tile[64][65];
  int t = threadIdx.x;
  int tr = t >> 4, tc = (t & 15) * 4;
#pragma unroll
  for (int i = 0; i < 4; ++i) {
    f32x4 v = *(const f32x4*)(in + (size_t)(tr + i * 16) * N + tc);
    tile[tr + i * 16][tc + 0] = v[0];
    tile[tr + i * 16][tc + 1] = v[1];
    tile[tr + i * 16][tc + 2] = v[2];
    tile[tr + i * 16][tc + 3] = v[3];
  }
  __syncthreads();
#pragma unroll
  for (int i = 0; i < 4; ++i) {
    int nr = tr + i * 16;
    u16x4 o;
    o[0] = f2bf(tile[tc + 0][nr]);
    o[1] = f2bf(tile[tc + 1][nr]);
    o[2] = f2bf(tile[tc + 2][nr]);
    o[3] = f2bf(tile[tc + 3][nr]);
    *(u16x4*)(out + (size_t)nr * K + tc) = o;
  }
}

// ---------------- embed: concat cls + pos add ------------------------------
__global__ __launch_bounds__(256)
void embed_k(const float* __restrict__ x, const float* __restrict__ cls,
             const float* __restrict__ pos, float* __restrict__ H)
{
  int row = blockIdx.x, t = threadIdx.x;
  int b_ = row >> 9, n = row & 511;
  int c = t * 4;
  f32x4 p = *(const f32x4*)(pos + (size_t)n * EMB + c);
  f32x4 s;
  if (n == 0) s = *(const f32x4*)(cls + c);
  else        s = *(const f32x4*)(x + ((size_t)b_ * 511 + (n - 1)) * EMB + c);
  f32x4 o = s + p;
  *(f32x4*)(H + (size_t)row * EMB + c) = o;
}

// ---------------- layernorm: fp32 h -> bf16 xn ----------------------------
__global__ __launch_bounds__(256)
void ln_k(const float* __restrict__ H, const float* __restrict__ g,
          const float* __restrict__ b, u16* __restrict__ out)
{
  int row = blockIdx.x, t = threadIdx.x;
  const float* hp = H + (size_t)row * EMB;
  f32x4 v = *(const f32x4*)(hp + t * 4);
  float s  = v[0] + v[1] + v[2] + v[3];
  float ss = v[0]*v[0] + v[1]*v[1] + v[2]*v[2] + v[3]*v[3];
#pragma unroll
  for (int m = 1; m <= 32; m <<= 1) { s += __shfl_xor(s, m); ss += __shfl_xor(ss, m); }
  __shared__ float red[8];
  if ((t & 63) == 0) { red[(t >> 6) * 2] = s; red[(t >> 6) * 2 + 1] = ss; }
  __syncthreads();
  float S  = red[0] + red[2] + red[4] + red[6];
  float SS = red[1] + red[3] + red[5] + red[7];
  float mean = S * (1.0f / EMB);
  float var  = SS * (1.0f / EMB) - mean * mean;
  float rs = rsqrtf(var + 1e-5f);
  f32x4 gg = *(const f32x4*)(g + t * 4);
  f32x4 bb = *(const f32x4*)(b + t * 4);
  u16x4 o;
#pragma unroll
  for (int i = 0; i < 4; ++i) o[i] = f2bf((v[i] - mean) * rs * gg[i] + bb[i]);
  *(u16x4*)(out + (size_t)row * EMB + t * 4) = o;
}

// ---------------- GEMM: C[8192][N] = A[8192][K] * Bt[N][K]^T --------------
// EPI: 0=QKV scatter(q,k,vT bf16)  1=+resid->H(f32)  2=+bias,gelu->outB(bf16)
//      3=+bias+resid->H(f32)
template<int EPI>
__global__ __launch_bounds__(256, 2)
void gemm_k(const u16* __restrict__ A, const u16* __restrict__ Bt,
            int nbn, int K,
            const float* __restrict__ bias, float* __restrict__ H,
            u16* __restrict__ outB,
            u16* __restrict__ qo, u16* __restrict__ ko, u16* __restrict__ vto)
{
  __shared__ u16 sm[2][2][128 * 64];   // 64 KB, double buffered A/B tiles
  // XCD-aware bijective swizzle (T1): contiguous bm-major chunk per XCD
  int cpx = gridDim.x >> 3;
  int logical = (blockIdx.x & 7) * cpx + (blockIdx.x >> 3);
  int bm = logical / nbn, bn = logical % nbn;
  int t = threadIdx.x, lane = t & 63, w = t >> 6;
  int wm = w >> 1, wn = w & 1;
  const u16* Ab = A  + (size_t)(bm * 128) * K;
  const u16* Bb = Bt + (size_t)(bn * 128) * K;
  int nkt = K >> 6;

  stage16k<128>(Ab, K, &sm[0][0][0]);
  stage16k<128>(Bb, K, &sm[0][1][0]);
  __syncthreads();

  const f32x4 vzero = {0.f, 0.f, 0.f, 0.f};
  f32x4 acc[4][4];
#pragma unroll
  for (int i = 0; i < 4; ++i)
#pragma unroll
    for (int j = 0; j < 4; ++j) acc[i][j] = vzero;

  int r0 = lane & 15;
  int kk0 = (lane >> 4) * 8;

  for (int kt = 0; kt < nkt; ++kt) {
    int cur = kt & 1;
    if (kt + 1 < nkt) {
      stage16k<128>(Ab + (kt + 1) * 64, K, &sm[cur ^ 1][0][0]);
      stage16k<128>(Bb + (kt + 1) * 64, K, &sm[cur ^ 1][1][0]);
    }
    const char* smA = (const char*)&sm[cur][0][0];
    const char* smB = (const char*)&sm[cur][1][0];
#pragma unroll
    for (int ks = 0; ks < 2; ++ks) {
      int kk = ks * 32 + kk0;
      bf16x8 a[4], b[4];
#pragma unroll
      for (int mf = 0; mf < 4; ++mf) {
        int row = wm * 64 + mf * 16 + r0;
        a[mf] = *(const bf16x8*)(smA + row * 128 + ((kk * 2) ^ ((row & 7) << 4)));
      }
#pragma unroll
      for (int nf = 0; nf < 4; ++nf) {
        int row = wn * 64 + nf * 16 + r0;
        b[nf] = *(const bf16x8*)(smB + row * 128 + ((kk * 2) ^ ((row & 7) << 4)));
      }
#pragma unroll
      for (int mf = 0; mf < 4; ++mf)
#pragma unroll
        for (int nf = 0; nf < 4; ++nf)
          acc[mf][nf] = __builtin_amdgcn_mfma_f32_16x16x32_bf16(a[mf], b[nf], acc[mf][nf], 0, 0, 0);
    }
    __syncthreads();
  }

  int m0 = bm * 128 + wm * 64;
  int n0 = bn * 128 + wn * 64;
  int hi = lane >> 4;
#pragma unroll
  for (int mf = 0; mf < 4; ++mf) {
#pragma unroll
    for (int nf = 0; nf < 4; ++nf) {
      int col  = n0 + nf * 16 + r0;
      int rowb = m0 + mf * 16 + hi * 4;
      if (EPI == 0) {
        int which = col >> 10, c = col & 1023;
        int hh = c >> 6, d = c & 63;
        int b_ = rowb >> 9, n_ = rowb & 511;
        size_t bh = (size_t)(b_ * NHEAD + hh);
        if (which == 2) {
          u16x4 o;
#pragma unroll
          for (int j = 0; j < 4; ++j) o[j] = f2bf(acc[mf][nf][j]);
          *(u16x4*)(vto + (bh * HDIM + d) * NSEQ + n_) = o;
        } else {
          u16* dst = (which == 0) ? qo : ko;
#pragma unroll
          for (int j = 0; j < 4; ++j)
            dst[(bh * NSEQ + n_ + j) * HDIM + d] = f2bf(acc[mf][nf][j]);
        }
      } else {
#pragma unroll
        for (int j = 0; j < 4; ++j) {
          int row = rowb + j;
          float v = acc[mf][nf][j];
          if (EPI == 1) {
            size_t idx = (size_t)row * EMB + col;
            H[idx] = v + H[idx];
          } else if (EPI == 2) {
            float xg = v + bias[col];
            float ge = 0.5f * xg * (1.0f + erff(xg * 0.70710678118654752f));
            outB[(size_t)row * FFD + col] = f2bf(ge);
          } else {
            size_t idx = (size_t)row * EMB + col;
            H[idx] = v + bias[col] + H[idx];
          }
        }
      }
    }
  }
}

// ---------------- fused attention -----------------------------------------
// grid: 2048 blocks (XCD-swizzled over (bh, qt)); block = 4 waves,
// each wave owns 16 q-rows. Q,K: [bh][512][64]; Vt: [bh][64][512]; AO bf16.
__global__ __launch_bounds__(256, 3)
void attn_k(const u16* __restrict__ Q, const u16* __restrict__ Kk,
            const u16* __restrict__ Vt, u16* __restrict__ AO)
{
  __shared__ u16 kv[2][8192];      // 32 KB staging (K chunks, then V chunks)
  __shared__ u16 Pt[4][2048];      // 16 KB: per-wave P^T chunk [128k][16q]
  int bid = blockIdx.x;
  int bh = (bid & 7) * 32 + (bid >> 6);      // all 8 q-tiles of a bh -> one XCD
  int qt = (bid >> 3) & 7;
  int t = threadIdx.x, lane = t & 63, w = t >> 6;
  const u16* Kb = Kk + (size_t)bh * (NSEQ * HDIM);
  const u16* Vb = Vt + (size_t)bh * (HDIM * NSEQ);
  int r0 = lane & 15, hi = lane >> 4, kk0 = hi * 8;

  int qrow = qt * 64 + w * 16 + r0;
  const u16* Qp = Q + ((size_t)bh * NSEQ + qrow) * HDIM;
  bf16x8 qf0 = *(const bf16x8*)(Qp + kk0);
  bf16x8 qf1 = *(const bf16x8*)(Qp + 32 + kk0);

  const f32x4 vzero = {0.f, 0.f, 0.f, 0.f};
  f32x4 accS[32];
#pragma unroll
  for (int f = 0; f < 32; ++f) accS[f] = vzero;

  // ---- S = Q K^T over 4 chunks of 128 keys ----
  stage16k<128>(Kb, HDIM, &kv[0][0]);
  __syncthreads();
#pragma unroll
  for (int kt = 0; kt < 4; ++kt) {
    if (kt < 3) stage16k<128>(Kb + (size_t)(kt + 1) * 128 * HDIM, HDIM, &kv[(kt + 1) & 1][0]);
    const char* smK = (const char*)&kv[kt & 1][0];
#pragma unroll
    for (int nfl = 0; nfl < 8; ++nfl) {
      int krow = nfl * 16 + r0;
      int swz = (krow & 7) << 4;
      bf16x8 b0 = *(const bf16x8*)(smK + krow * 128 + (((kk0)      * 2) ^ swz));
      bf16x8 b1 = *(const bf16x8*)(smK + krow * 128 + (((32 + kk0) * 2) ^ swz));
      accS[kt * 8 + nfl] = __builtin_amdgcn_mfma_f32_16x16x32_bf16(qf0, b0, accS[kt * 8 + nfl], 0, 0, 0);
      accS[kt * 8 + nfl] = __builtin_amdgcn_mfma_f32_16x16x32_bf16(qf1, b1, accS[kt * 8 + nfl], 0, 0, 0);
    }
    __syncthreads();
  }

  // prefetch V chunk 0 under the softmax
  stage16k<256>(Vb, NSEQ, &kv[0][0]);

  // ---- softmax over 512 keys (accS: key=f*16+r0, query=4*hi+j) ----------
  float mx[4], den[4], rden[4];
#pragma unroll
  for (int j = 0; j < 4; ++j) {
    float m = -1e30f;
#pragma unroll
    for (int f = 0; f < 32; ++f) m = fmaxf(m, accS[f][j]);
    m = fmaxf(m, __shfl_xor(m, 1));
    m = fmaxf(m, __shfl_xor(m, 2));
    m = fmaxf(m, __shfl_xor(m, 4));
    m = fmaxf(m, __shfl_xor(m, 8));
    mx[j] = m;
    den[j] = 0.f;
  }
  // exp + pack to bf16 pairs (frees accS before PV; VGPR 128 -> 64)
  uint32_t pb[64];
#pragma unroll
  for (int f = 0; f < 32; ++f) {
    float p0 = __expf((accS[f][0] - mx[0]) * 0.03125f);
    float p1 = __expf((accS[f][1] - mx[1]) * 0.03125f);
    float p2 = __expf((accS[f][2] - mx[2]) * 0.03125f);
    float p3 = __expf((accS[f][3] - mx[3]) * 0.03125f);
    den[0] += p0; den[1] += p1; den[2] += p2; den[3] += p3;
    pb[f * 2 + 0] = (uint32_t)f2bf(p0) | ((uint32_t)f2bf(p1) << 16);
    pb[f * 2 + 1] = (uint32_t)f2bf(p2) | ((uint32_t)f2bf(p3) << 16);
  }
#pragma unroll
  for (int j = 0; j < 4; ++j) {
    float d = den[j];
    d += __shfl_xor(d, 1); d += __shfl_xor(d, 2);
    d += __shfl_xor(d, 4); d += __shfl_xor(d, 8);
    rden[j] = 1.0f / d;
  }
  __syncthreads();   // V chunk0 staged (barrier drains vmcnt)

  // ---- O = P V over 4 chunks of 128 keys --------------------------------
  // P^T chunk layout: per 32-key block, row' = tile*16 + (kb>>3)*4 + (kb&3),
  // tile = (kb>>2)&1  -> two ds_read_b64_tr_b16 yield the x32 A-fragment
  // (k = 8*hi + j). perm for this lane's key (kb = (fl&1)*16 + r0):
  int perm0 = ((r0 & 4) << 2) + ((r0 >> 3) << 2) + (r0 & 3);
  uint32_t ptb = (uint32_t)(uintptr_t)(as3_u16p)&Pt[w][0];
  uint32_t trBase = ptb + r0 * 2 + hi * 128;   // + s*1024 (+512 for tile1)
  char* PtW = (char*)&Pt[w][0];

  f32x4 accO[4];
#pragma unroll
  for (int nf = 0; nf < 4; ++nf) accO[nf] = vzero;

#pragma unroll
  for (int kt = 0; kt < 4; ++kt) {
    if (kt < 3) stage16k<256>(Vb + (kt + 1) * 128, NSEQ, &kv[(kt + 1) & 1][0]);
    // write this chunk's P^T (wave-private, b64 stores)
#pragma unroll
    for (int fl = 0; fl < 8; ++fl) {
      int f = kt * 8 + fl;
      int row = (fl >> 1) * 32 + perm0 + ((fl & 1) << 3);
      *(uint2*)(PtW + row * 32 + hi * 8) = make_uint2(pb[f * 2], pb[f * 2 + 1]);
    }
    asm volatile("s_waitcnt lgkmcnt(0)" ::: "memory");   // P^T visible to own wave
    const char* smV = (const char*)&kv[kt & 1][0];
#pragma unroll
    for (int s = 0; s < 4; ++s) {
      uint2 t0, t1;
      uint32_t a0 = trBase + s * 1024;
      asm volatile("ds_read_b64_tr_b16 %0, %1" : "=v"(t0) : "v"(a0) : "memory");
      asm volatile("ds_read_b64_tr_b16 %0, %1" : "=v"(t1) : "v"(a0 + 512) : "memory");
      bf16x8 vb[4];
#pragma unroll
      for (int nf = 0; nf < 4; ++nf) {
        int d = nf * 16 + r0;
        int inrow = s * 64 + hi * 16;
        vb[nf] = *(const bf16x8*)(smV + d * 256 + (inrow ^ ((d & 7) << 4)));
      }
      asm volatile("s_waitcnt lgkmcnt(0)" ::: "memory");
      __builtin_amdgcn_sched_barrier(0);
      union { uint4 u; bf16x8 v; } pa;
      pa.u = make_uint4(t0.x, t0.y, t1.x, t1.y);
#pragma unroll
      for (int nf = 0; nf < 4; ++nf)
        accO[nf] = __builtin_amdgcn_mfma_f32_16x16x32_bf16(pa.v, vb[nf], accO[nf], 0, 0, 0);
    }
    __syncthreads();
  }

  // ---- epilogue: normalize, scatter back to [b][n][h*64+d] --------------
  int b_ = bh >> 4, hh = bh & 15;
#pragma unroll
  for (int nf = 0; nf < 4; ++nf)
#pragma unroll
    for (int j = 0; j < 4; ++j) {
      int ql = hi * 4 + j;
      int tok = qt * 64 + w * 16 + ql;
      int col = hh * 64 + nf * 16 + r0;
      AO[((size_t)(b_ * NSEQ + tok)) * EMB + col] = f2bf(accO[nf][j] * rden[j]);
    }
}

// ---------------- launch ---------------------------------------------------
extern "C" void kernel_launch(void* const* d_in, const int* in_sizes, int n_in,
                              void* d_out, int out_size, void* d_ws, size_t ws_size,
                              hipStream_t stream)
{
  const float* x    = (const float*)d_in[0];
  const float* cls  = (const float*)d_in[1];
  const float* pos  = (const float*)d_in[2];
  const float* Wq   = (const float*)d_in[3];
  const float* Wk   = (const float*)d_in[4];
  const float* Wv   = (const float*)d_in[5];
  const float* Wp   = (const float*)d_in[6];
  const float* ln1g = (const float*)d_in[7];
  const float* ln1b = (const float*)d_in[8];
  const float* ln2g = (const float*)d_in[9];
  const float* ln2b = (const float*)d_in[10];
  const float* W1   = (const float*)d_in[11];
  const float* b1   = (const float*)d_in[12];
  const float* W2   = (const float*)d_in[13];
  const float* b2   = (const float*)d_in[14];
  float* H = (float*)d_out;          // residual stream lives in d_out (fp32)

  char* ws = (char*)d_ws;            // 160 MiB used
  u16* wqkv = (u16*)(ws + 0);                // [6][3072][1024] bf16 (B^T)
  u16* wp   = (u16*)(ws + 37748736);         // [6][1024][1024]
  u16* w1t  = (u16*)(ws + 50331648);         // [6][2048][1024]
  u16* w2t  = (u16*)(ws + 75497472);         // [6][1024][2048]
  u16* xn   = (u16*)(ws + 100663296);        // [8192][1024] (also attn out)
  u16* qb   = (u16*)(ws + 117440512);        // [256][512][64]
  u16* kb   = (u16*)(ws + 134217728);        // [256][512][64]
  u16* vtb  = (u16*)(ws + 150994944);        // [256][64][512]
  u16* ffb  = qb;                            // [8192][2048] aliases q+k

  wprep_k<<<1536, 256, 0, stream>>>(Wq, wqkv, 1024, 1024, 1048576, 3145728, 0);
  wprep_k<<<1536, 256, 0, stream>>>(Wk, wqkv, 1024, 1024, 1048576, 3145728, 1048576);
  wprep_k<<<1536, 256, 0, stream>>>(Wv, wqkv, 1024, 1024, 1048576, 3145728, 2097152);
  wprep_k<<<1536, 256, 0, stream>>>(Wp, wp,   1024, 1024, 1048576, 1048576, 0);
  wprep_k<<<3072, 256, 0, stream>>>(W1, w1t,  1024, 2048, 2097152, 2097152, 0);
  wprep_k<<<3072, 256, 0, stream>>>(W2, w2t,  2048, 1024, 2097152, 2097152, 0);

  embed_k<<<NTOK, 256, 0, stream>>>(x, cls, pos, H);

  for (int l = 0; l < DEPTH; ++l) {
    ln_k<<<NTOK, 256, 0, stream>>>(H, ln1g + l * EMB, ln1b + l * EMB, xn);
    gemm_k<0><<<64 * 24, 256, 0, stream>>>(xn, wqkv + (size_t)l * 3145728, 24, 1024,
                                           nullptr, nullptr, nullptr, qb, kb, vtb);
    attn_k<<<2048, 256, 0, stream>>>(qb, kb, vtb, xn);
    gemm_k<1><<<64 * 8, 256, 0, stream>>>(xn, wp + (size_t)l * 1048576, 8, 1024,
                                          nullptr, H, nullptr, nullptr, nullptr, nullptr);
    ln_k<<<NTOK, 256, 0, stream>>>(H, ln2g + l * EMB, ln2b + l * EMB, xn);
    gemm_k<2><<<64 * 16, 256, 0, stream>>>(xn, w1t + (size_t)l * 2097152, 16, 1024,
                                           b1 + l * FFD, nullptr, ffb, nullptr, nullptr, nullptr);
    gemm_k<3><<<64 * 8, 256, 0, stream>>>(ffb, w2t + (size_t)l * 2097152, 8, 2048,
                                          b2 + l * EMB, H, nullptr, nullptr, nullptr, nullptr);
  }
}